// Round 1
// baseline (133.619 us; speedup 1.0000x reference)
//
#include <hip/hip_runtime.h>
#include <math.h>

#define NTHREADS 256
#define NROWS 8192
#define NCOLS 8192
#define VPT 8  // float4 loads per thread: 8 * 4 * 256 = 8192 columns

// ---------- stage 1: one block per row ----------
__global__ __launch_bounds__(NTHREADS)
void bitempered_row_kernel(const float* __restrict__ act,
                           const int* __restrict__ labels,
                           float* __restrict__ row_loss)
{
    __shared__ float sm[4];
    const int row  = blockIdx.x;
    const int tid  = threadIdx.x;
    const int lane = tid & 63;
    const int wid  = tid >> 6;

    const float4* rp = reinterpret_cast<const float4*>(act + (size_t)row * NCOLS);
    float4 v[VPT];
#pragma unroll
    for (int k = 0; k < VPT; ++k) v[k] = rp[tid + k * NTHREADS];

    // ---- row max ----
    float mx = -INFINITY;
#pragma unroll
    for (int k = 0; k < VPT; ++k)
        mx = fmaxf(mx, fmaxf(fmaxf(v[k].x, v[k].y), fmaxf(v[k].z, v[k].w)));
#pragma unroll
    for (int o = 32; o >= 1; o >>= 1) mx = fmaxf(mx, __shfl_xor(mx, o, 64));
    if (lane == 0) sm[wid] = mx;
    __syncthreads();
    mx = fmaxf(fmaxf(sm[0], sm[1]), fmaxf(sm[2], sm[3]));
    __syncthreads();

    // ---- a0 = act - mu  (<= 0) ----
#pragma unroll
    for (int k = 0; k < VPT; ++k) {
        v[k].x -= mx; v[k].y -= mx; v[k].z -= mx; v[k].w -= mx;
    }

    // ---- fixed point: 5 iterations + final z ----
    // a = a0 * w,  w = z^(1-T2) = z^-0.4
    // exp_t(a,1.4) = (1 - 0.4*a)^(-2.5) = rsqrt(b)^5,  b = 1 - 0.4*w*a0 >= 1
    float w = 1.0f;
    float z = 0.0f;
#pragma unroll 1
    for (int it = 0; it < 6; ++it) {
        const float nw = -0.4f * w;
        float part = 0.0f;
#pragma unroll
        for (int k = 0; k < VPT; ++k) {
            float c[4] = {v[k].x, v[k].y, v[k].z, v[k].w};
#pragma unroll
            for (int j = 0; j < 4; ++j) {
                float b  = fmaf(c[j], nw, 1.0f);
                float t  = rsqrtf(b);
                float t2 = t * t;
                part += t2 * t2 * t;   // b^-2.5
            }
        }
#pragma unroll
        for (int o = 32; o >= 1; o >>= 1) part += __shfl_xor(part, o, 64);
        if (lane == 0) sm[wid] = part;
        __syncthreads();
        z = (sm[0] + sm[1]) + (sm[2] + sm[3]);
        __syncthreads();
        if (it < 5) w = exp2f(-0.4f * log2f(z));
    }
    const float Z04 = exp2f(0.4f * log2f(z));   // z_final^0.4

    // ---- final loss pass ----
    // base = z^0.4 - 0.4*a0 ;  p^0.2 = rsqrt(base) ;  p^1.2 = base^-3
    const int   label = labels[row];
    const float off_y = 0.1f / 8191.0f;
    const float c1 = -5.0f * off_y;                 // -off/(1-T1) factor: -off*5
    const float c2 = -5.0f * (0.9f - off_y);        // label correction
    float acc = 0.0f;
#pragma unroll
    for (int k = 0; k < VPT; ++k) {
        const int c0 = 4 * (tid + k * NTHREADS);
        float c[4] = {v[k].x, v[k].y, v[k].z, v[k].w};
#pragma unroll
        for (int j = 0; j < 4; ++j) {
            float b   = fmaf(c[j], -0.4f, Z04);
            float s   = rsqrtf(b);       // p^0.2
            float q   = s * s;           // base^-1
            float p12 = q * q * q;       // p^1.2
            float e   = c1 * (s - 1.0f) + p12 * (1.0f / 1.2f);
            if (c0 + j == label) e += c2 * (s - 1.0f);
            acc += e;
        }
    }
#pragma unroll
    for (int o = 32; o >= 1; o >>= 1) acc += __shfl_xor(acc, o, 64);
    if (lane == 0) sm[wid] = acc;
    __syncthreads();
    if (tid == 0) row_loss[row] = (sm[0] + sm[1]) + (sm[2] + sm[3]);
}

// ---------- stage 2: reduce 8192 row losses -> scalar mean (+K) ----------
__global__ __launch_bounds__(256)
void bitempered_final_kernel(const float* __restrict__ row_loss,
                             float* __restrict__ out, double K)
{
    __shared__ double sm[4];
    const int tid = threadIdx.x;
    double s = 0.0;
    for (int i = tid; i < NROWS; i += 256) s += (double)row_loss[i];
#pragma unroll
    for (int o = 32; o >= 1; o >>= 1) s += __shfl_xor(s, o, 64);
    const int lane = tid & 63, wid = tid >> 6;
    if (lane == 0) sm[wid] = s;
    __syncthreads();
    if (tid == 0) {
        double tot = sm[0] + sm[1] + sm[2] + sm[3];
        out[0] = (float)(tot / (double)NROWS + K);
    }
}

extern "C" void kernel_launch(void* const* d_in, const int* in_sizes, int n_in,
                              void* d_out, int out_size, void* d_ws, size_t ws_size,
                              hipStream_t stream)
{
    const float* act    = (const float*)d_in[0];
    const int*   labels = (const int*)d_in[1];
    float* out      = (float*)d_out;
    float* row_loss = (float*)d_ws;   // 8192 floats

    // Row-independent smoothed-label constant, in double:
    // K = sum_c [ y_c * log_t(y_c + 1e-10, T1) - y_c^(2-T1)/(2-T1) ]
    const double off_y = 0.1 / 8191.0;
    const double on_y  = 0.9;
    auto logt1 = [](double u) { return (pow(u, 0.2) - 1.0) / 0.2; };
    const double K = 8191.0 * (off_y * logt1(off_y + 1e-10) - pow(off_y, 1.2) / 1.2)
                   + (on_y * logt1(on_y + 1e-10) - pow(on_y, 1.2) / 1.2);

    bitempered_row_kernel<<<NROWS, NTHREADS, 0, stream>>>(act, labels, row_loss);
    bitempered_final_kernel<<<1, 256, 0, stream>>>(row_loss, out, K);
}

// Round 2
// 108.054 us; speedup vs baseline: 1.2366x; 1.2366x over previous
//
#include <hip/hip_runtime.h>
#include <math.h>

#define NTHREADS 256
#define NROWS 8192
#define NCOLS 8192
#define VPT 8  // float4 loads per thread: 8 * 4 * 256 = 8192 columns

__device__ __forceinline__ float fast_rsqrt(float x) {
#if __has_builtin(__builtin_amdgcn_rsqf)
    return __builtin_amdgcn_rsqf(x);   // raw v_rsq_f32, ~1 ulp
#else
    return rsqrtf(x);
#endif
}
__device__ __forceinline__ float fast_exp2(float x) {
#if __has_builtin(__builtin_amdgcn_exp2f)
    return __builtin_amdgcn_exp2f(x);  // raw v_exp_f32
#else
    return exp2f(x);
#endif
}
__device__ __forceinline__ float fast_log2(float x) {
#if __has_builtin(__builtin_amdgcn_logf)
    return __builtin_amdgcn_logf(x);   // raw v_log_f32 (base-2)
#else
    return log2f(x);
#endif
}

// ---------- stage 1: one block per row ----------
__global__ __launch_bounds__(NTHREADS)
void bitempered_row_kernel(const float* __restrict__ act,
                           const int* __restrict__ labels,
                           float* __restrict__ row_loss)
{
    __shared__ float sm[4];
    const int row  = blockIdx.x;
    const int tid  = threadIdx.x;
    const int lane = tid & 63;
    const int wid  = tid >> 6;

    const float4* rp = reinterpret_cast<const float4*>(act + (size_t)row * NCOLS);
    float4 v[VPT];
#pragma unroll
    for (int k = 0; k < VPT; ++k) v[k] = rp[tid + k * NTHREADS];

    // ---- row max ----
    float mx = -INFINITY;
#pragma unroll
    for (int k = 0; k < VPT; ++k)
        mx = fmaxf(mx, fmaxf(fmaxf(v[k].x, v[k].y), fmaxf(v[k].z, v[k].w)));
#pragma unroll
    for (int o = 32; o >= 1; o >>= 1) mx = fmaxf(mx, __shfl_xor(mx, o, 64));
    if (lane == 0) sm[wid] = mx;
    __syncthreads();
    mx = fmaxf(fmaxf(sm[0], sm[1]), fmaxf(sm[2], sm[3]));
    __syncthreads();

    // ---- a0 = act - mu  (<= 0) ----
#pragma unroll
    for (int k = 0; k < VPT; ++k) {
        v[k].x -= mx; v[k].y -= mx; v[k].z -= mx; v[k].w -= mx;
    }

    // ---- fixed point: 5 iterations + final z ----
    // a = a0 * w,  w = z^(1-T2) = z^-0.4
    // exp_t(a,1.4) = (1 - 0.4*a)^(-2.5) = rsqrt(b)^5,  b = 1 - 0.4*w*a0 >= 1
    float w = 1.0f;
    float z = 0.0f;
#pragma unroll 1
    for (int it = 0; it < 6; ++it) {
        const float nw = -0.4f * w;
        float part = 0.0f;
#pragma unroll
        for (int k = 0; k < VPT; ++k) {
            float c[4] = {v[k].x, v[k].y, v[k].z, v[k].w};
#pragma unroll
            for (int j = 0; j < 4; ++j) {
                float b  = fmaf(c[j], nw, 1.0f);
                float t  = fast_rsqrt(b);
                float t2 = t * t;
                float t4 = t2 * t2;
                part = fmaf(t4, t, part);   // += b^-2.5
            }
        }
#pragma unroll
        for (int o = 32; o >= 1; o >>= 1) part += __shfl_xor(part, o, 64);
        if (lane == 0) sm[wid] = part;
        __syncthreads();
        z = (sm[0] + sm[1]) + (sm[2] + sm[3]);
        __syncthreads();
        if (it < 5) w = fast_exp2(-0.4f * fast_log2(z));
    }
    const float Z04 = fast_exp2(0.4f * fast_log2(z));   // z_final^0.4

    // ---- final loss pass ----
    // base = z^0.4 - 0.4*a0 ;  p^0.2 = rsqrt(base) ;  p^1.2 = base^-3
    const int   label = labels[row];
    const float off_y = 0.1f / 8191.0f;
    const float c1 = -5.0f * off_y;                 // -off/(1-T1) factor: -off*5
    const float c2 = -5.0f * (0.9f - off_y);        // label correction
    float acc = 0.0f;
#pragma unroll
    for (int k = 0; k < VPT; ++k) {
        const int c0 = 4 * (tid + k * NTHREADS);
        float c[4] = {v[k].x, v[k].y, v[k].z, v[k].w};
#pragma unroll
        for (int j = 0; j < 4; ++j) {
            float b   = fmaf(c[j], -0.4f, Z04);
            float s   = fast_rsqrt(b);   // p^0.2
            float q   = s * s;           // base^-1
            float p12 = q * q * q;       // p^1.2
            float e   = fmaf(p12, (1.0f / 1.2f), c1 * (s - 1.0f));
            if (c0 + j == label) e = fmaf(c2, (s - 1.0f), e);
            acc += e;
        }
    }
#pragma unroll
    for (int o = 32; o >= 1; o >>= 1) acc += __shfl_xor(acc, o, 64);
    if (lane == 0) sm[wid] = acc;
    __syncthreads();
    if (tid == 0) row_loss[row] = (sm[0] + sm[1]) + (sm[2] + sm[3]);
}

// ---------- stage 2: reduce 8192 row losses -> scalar mean (+K) ----------
__global__ __launch_bounds__(256)
void bitempered_final_kernel(const float* __restrict__ row_loss,
                             float* __restrict__ out, double K)
{
    __shared__ double sm[4];
    const int tid = threadIdx.x;
    double s = 0.0;
    for (int i = tid; i < NROWS; i += 256) s += (double)row_loss[i];
#pragma unroll
    for (int o = 32; o >= 1; o >>= 1) s += __shfl_xor(s, o, 64);
    const int lane = tid & 63, wid = tid >> 6;
    if (lane == 0) sm[wid] = s;
    __syncthreads();
    if (tid == 0) {
        double tot = sm[0] + sm[1] + sm[2] + sm[3];
        out[0] = (float)(tot / (double)NROWS + K);
    }
}

extern "C" void kernel_launch(void* const* d_in, const int* in_sizes, int n_in,
                              void* d_out, int out_size, void* d_ws, size_t ws_size,
                              hipStream_t stream)
{
    const float* act    = (const float*)d_in[0];
    const int*   labels = (const int*)d_in[1];
    float* out      = (float*)d_out;
    float* row_loss = (float*)d_ws;   // 8192 floats

    // Row-independent smoothed-label constant, in double:
    // K = sum_c [ y_c * log_t(y_c + 1e-10, T1) - y_c^(2-T1)/(2-T1) ]
    const double off_y = 0.1 / 8191.0;
    const double on_y  = 0.9;
    auto logt1 = [](double u) { return (pow(u, 0.2) - 1.0) / 0.2; };
    const double K = 8191.0 * (off_y * logt1(off_y + 1e-10) - pow(off_y, 1.2) / 1.2)
                   + (on_y * logt1(on_y + 1e-10) - pow(on_y, 1.2) / 1.2);

    bitempered_row_kernel<<<NROWS, NTHREADS, 0, stream>>>(act, labels, row_loss);
    bitempered_final_kernel<<<1, 256, 0, stream>>>(row_loss, out, K);
}

// Round 3
// 90.793 us; speedup vs baseline: 1.4717x; 1.1901x over previous
//
#include <hip/hip_runtime.h>
#include <math.h>

#define NTHREADS 256
#define NROWS 8192
#define NCOLS 8192
#define VPT 8                 // float4 per thread: 8*4*256 = 8192 cols
#define RPB 4                 // rows per block
#define NBLOCKS (NROWS / RPB) // 2048

__device__ __forceinline__ float fast_rsqrt(float x) {
#if __has_builtin(__builtin_amdgcn_rsqf)
    return __builtin_amdgcn_rsqf(x);
#else
    return rsqrtf(x);
#endif
}
__device__ __forceinline__ float fast_exp2(float x) {
#if __has_builtin(__builtin_amdgcn_exp2f)
    return __builtin_amdgcn_exp2f(x);
#else
    return exp2f(x);
#endif
}
__device__ __forceinline__ float fast_log2(float x) {
#if __has_builtin(__builtin_amdgcn_logf)
    return __builtin_amdgcn_logf(x);
#else
    return log2f(x);
#endif
}

// Process one row held in cur[]; optionally issue prefetch of row pf into nxt[].
// S(w) = sum_j (1 - 0.4*w*a0_j)^-2.5 ; z1 = S(1) exact, iterations 2..final via
// degree-10 binomial series: S(w) = sum_k d_k w^k M_k, M_k = sum a0^k.
__device__ __forceinline__ void process_row(
    const float* __restrict__ act, const int* __restrict__ labels,
    float* __restrict__ row_loss, int row, float4* cur, float4* nxt, int pf,
    int tid, int lane, int wid, float (*sm)[16])
{
    // ---- phase 1: row max ----
    float mx = -INFINITY;
#pragma unroll
    for (int k = 0; k < VPT; ++k)
        mx = fmaxf(mx, fmaxf(fmaxf(cur[k].x, cur[k].y), fmaxf(cur[k].z, cur[k].w)));
#pragma unroll
    for (int o = 32; o >= 1; o >>= 1) mx = fmaxf(mx, __shfl_xor(mx, o, 64));
    if (lane == 0) sm[wid][0] = mx;
    __syncthreads();
    mx = fmaxf(fmaxf(sm[0][0], sm[1][0]), fmaxf(sm[2][0], sm[3][0]));

    // ---- prefetch next row (waited at next row's max phase) ----
    if (pf >= 0) {
        const float4* rp = reinterpret_cast<const float4*>(act + (size_t)pf * NCOLS);
#pragma unroll
        for (int k = 0; k < VPT; ++k) nxt[k] = rp[tid + k * NTHREADS];
    }

    // ---- phase 2: sweep A — z1 = S(1) exact + power sums M1..M10 ----
    float z1 = 0.f;
    float m1 = 0.f, m2 = 0.f, m3 = 0.f, m4 = 0.f, m5 = 0.f;
    float m6 = 0.f, m7 = 0.f, m8 = 0.f, m9 = 0.f, m10 = 0.f;
#pragma unroll
    for (int k = 0; k < VPT; ++k) {
        float c[4] = {cur[k].x - mx, cur[k].y - mx, cur[k].z - mx, cur[k].w - mx};
        cur[k].x = c[0]; cur[k].y = c[1]; cur[k].z = c[2]; cur[k].w = c[3];
#pragma unroll
        for (int j = 0; j < 4; ++j) {
            float a  = c[j];
            float b  = fmaf(a, -0.4f, 1.0f);   // >= 1
            float t  = fast_rsqrt(b);
            float t2 = t * t;
            float t4 = t2 * t2;
            z1 = fmaf(t4, t, z1);              // += b^-2.5
            float p2 = a * a;
            float p4 = p2 * p2;
            float p6 = p4 * p2;
            float p8 = p4 * p4;
            m1 += a;
            m2 += p2;
            m3 = fmaf(p2, a, m3);
            m4 += p4;
            m5 = fmaf(p4, a, m5);
            m6 += p6;
            m7 = fmaf(p6, a, m7);
            m8 += p8;
            m9  = fmaf(p8, a,  m9);
            m10 = fmaf(p8, p2, m10);
        }
    }
    float red[11] = {z1, m1, m2, m3, m4, m5, m6, m7, m8, m9, m10};
#pragma unroll
    for (int i = 0; i < 11; ++i) {
#pragma unroll
        for (int o = 32; o >= 1; o >>= 1) red[i] += __shfl_xor(red[i], o, 64);
    }
    if (lane == 0) {
#pragma unroll
        for (int i = 0; i < 11; ++i) sm[wid][1 + i] = red[i];
    }
    __syncthreads();
    float M[11];
#pragma unroll
    for (int i = 0; i < 11; ++i)
        M[i] = (sm[0][1 + i] + sm[1][1 + i]) + (sm[2][1 + i] + sm[3][1 + i]);

    // d_k = binom(-2.5,k) * (-0.4)^k  (all positive-signed via M_k's sign)
    const float H0  = (float)NCOLS;            // M0 = 8192
    const float H1  = 1.0f           * M[1];
    const float H2  = 0.7f           * M[2];
    const float H3  = 0.42f          * M[3];
    const float H4  = 0.231f         * M[4];
    const float H5  = 0.12012f       * M[5];
    const float H6  = 0.060060060f   * M[6];
    const float H7  = 0.029172029f   * M[7];
    const float H8  = 0.013856714f   * M[8];
    const float H9  = 0.0064664665f  * M[9];
    const float H10 = 0.0029745746f  * M[10];

    float w = fast_exp2(-0.4f * fast_log2(M[0]));   // w1 from exact z1
    float z = M[0];
#pragma unroll
    for (int it = 0; it < 5; ++it) {
        float h = fmaf(H10, w, H9);
        h = fmaf(h, w, H8);
        h = fmaf(h, w, H7);
        h = fmaf(h, w, H6);
        h = fmaf(h, w, H5);
        h = fmaf(h, w, H4);
        h = fmaf(h, w, H3);
        h = fmaf(h, w, H2);
        h = fmaf(h, w, H1);
        z = fmaf(h, w, H0);                         // z_{it+2} = S(w)
        if (it < 4) w = fast_exp2(-0.4f * fast_log2(z));
    }
    const float Z04 = fast_exp2(0.4f * fast_log2(z));   // z_final^0.4

    // ---- phase 3: final loss pass ----
    // base = Z04 - 0.4*a0 ; p^0.2 = rsqrt(base) ; p^1.2 = base^-3
    float acc_s = 0.f, acc_p = 0.f;
#pragma unroll
    for (int k = 0; k < VPT; ++k) {
        float c[4] = {cur[k].x, cur[k].y, cur[k].z, cur[k].w};
#pragma unroll
        for (int j = 0; j < 4; ++j) {
            float b  = fmaf(c[j], -0.4f, Z04);
            float s  = fast_rsqrt(b);
            float q  = s * s;
            float q2 = q * q;
            acc_s += s;
            acc_p = fmaf(q2, q, acc_p);
        }
    }
#pragma unroll
    for (int o = 32; o >= 1; o >>= 1) {
        acc_s += __shfl_xor(acc_s, o, 64);
        acc_p += __shfl_xor(acc_p, o, 64);
    }
    if (lane == 0) { sm[wid][12] = acc_s; sm[wid][13] = acc_p; }
    __syncthreads();
    if (tid == 0) {
        float S = (sm[0][12] + sm[1][12]) + (sm[2][12] + sm[3][12]);
        float P = (sm[0][13] + sm[1][13]) + (sm[2][13] + sm[3][13]);
        int   label = labels[row];
        float al = act[(size_t)row * NCOLS + label] - mx;
        float sl = fast_rsqrt(fmaf(al, -0.4f, Z04));
        const float off_y = 0.1f / 8191.0f;
        const float c1 = -5.0f * off_y;
        const float c2 = -5.0f * (0.9f - off_y);
        row_loss[row] = c1 * (S - (float)NCOLS) + P * (1.0f / 1.2f)
                      + c2 * (sl - 1.0f);
    }
}

__global__ __launch_bounds__(NTHREADS, 4)
void bitempered_row_kernel(const float* __restrict__ act,
                           const int* __restrict__ labels,
                           float* __restrict__ row_loss)
{
    __shared__ float sm[4][16];
    const int tid  = threadIdx.x;
    const int lane = tid & 63;
    const int wid  = tid >> 6;
    const int base = blockIdx.x * RPB;

    float4 bufA[VPT], bufB[VPT];
    {
        const float4* rp = reinterpret_cast<const float4*>(act + (size_t)base * NCOLS);
#pragma unroll
        for (int k = 0; k < VPT; ++k) bufA[k] = rp[tid + k * NTHREADS];
    }

#pragma unroll 1
    for (int rr = 0; rr < RPB; rr += 2) {
        process_row(act, labels, row_loss, base + rr,     bufA, bufB,
                    base + rr + 1, tid, lane, wid, sm);
        process_row(act, labels, row_loss, base + rr + 1, bufB, bufA,
                    (rr + 2 < RPB) ? (base + rr + 2) : -1, tid, lane, wid, sm);
    }
}

// ---------- stage 2: reduce 8192 row losses -> scalar mean (+K) ----------
__global__ __launch_bounds__(256)
void bitempered_final_kernel(const float* __restrict__ row_loss,
                             float* __restrict__ out, double K)
{
    __shared__ double smd[4];
    const int tid = threadIdx.x;
    double s = 0.0;
    for (int i = tid; i < NROWS; i += 256) s += (double)row_loss[i];
#pragma unroll
    for (int o = 32; o >= 1; o >>= 1) s += __shfl_xor(s, o, 64);
    const int lane = tid & 63, wid = tid >> 6;
    if (lane == 0) smd[wid] = s;
    __syncthreads();
    if (tid == 0) {
        double tot = smd[0] + smd[1] + smd[2] + smd[3];
        out[0] = (float)(tot / (double)NROWS + K);
    }
}

extern "C" void kernel_launch(void* const* d_in, const int* in_sizes, int n_in,
                              void* d_out, int out_size, void* d_ws, size_t ws_size,
                              hipStream_t stream)
{
    const float* act    = (const float*)d_in[0];
    const int*   labels = (const int*)d_in[1];
    float* out      = (float*)d_out;
    float* row_loss = (float*)d_ws;   // 8192 floats

    // Row-independent smoothed-label constant, in double:
    // K = sum_c [ y_c * log_t(y_c + 1e-10, T1) - y_c^(2-T1)/(2-T1) ]
    const double off_y = 0.1 / 8191.0;
    const double on_y  = 0.9;
    auto logt1 = [](double u) { return (pow(u, 0.2) - 1.0) / 0.2; };
    const double K = 8191.0 * (off_y * logt1(off_y + 1e-10) - pow(off_y, 1.2) / 1.2)
                   + (on_y * logt1(on_y + 1e-10) - pow(on_y, 1.2) / 1.2);

    bitempered_row_kernel<<<NBLOCKS, NTHREADS, 0, stream>>>(act, labels, row_loss);
    bitempered_final_kernel<<<1, 256, 0, stream>>>(row_loss, out, K);
}